// Round 11
// baseline (232.935 us; speedup 1.0000x reference)
//
#include <hip/hip_runtime.h>
#include <hip/hip_bf16.h>
#include <math.h>

#define NNODES 100000
#define FIN 500
#define KPAD 512
#define HIDDIM 64
#define NCLS 40
#define KORD 10

typedef __bf16 bf16x4 __attribute__((ext_vector_type(4)));
typedef __bf16 bf16x8 __attribute__((ext_vector_type(8)));
typedef float f32x4 __attribute__((ext_vector_type(4)));

// ---------------- polynomial coefficients + need-flags from temp ----------------
// out = sum_j C(K,j)/2^K * relu(temp[j]) * (I-A)^j (I+A)^{K-j} h = sum_m g[m] A^m h
// g[m] = sum_j s_j * T[j][m], T[j][m] = coeff of x^m in (1-x)^j (1+x)^{K-j}.
// All intermediates are integers/1024 with numerators < 2^24, exact in f32.
// flags[m] = 1 iff any g[j] != 0 for j >= m  (SpMV step m still needed).
__global__ void coeff_kernel(const float* __restrict__ temp, float* __restrict__ g,
                             int* __restrict__ flags) {
  if (threadIdx.x != 0 || blockIdx.x != 0) return;
  float C[KORD + 1][KORD + 1];
  for (int n = 0; n <= KORD; ++n)
    for (int k = 0; k <= KORD; ++k) C[n][k] = 0.f;
  for (int n = 0; n <= KORD; ++n) {
    C[n][0] = 1.f;
    for (int k = 1; k <= n; ++k) C[n][k] = C[n - 1][k - 1] + C[n - 1][k];
  }
  float s[KORD + 1];
  for (int j = 0; j <= KORD; ++j) {
    float th = temp[j] > 0.f ? temp[j] : 0.f;
    s[j] = C[KORD][j] * (1.0f / 1024.0f) * th;
  }
  for (int m = 0; m <= KORD; ++m) {
    float acc = 0.f;
    for (int j = 0; j <= KORD; ++j) {
      float T = 0.f;
      for (int a = 0; a <= m; ++a) {
        int b = m - a;
        if (a <= j && b <= KORD - j)
          T += ((a & 1) ? -1.f : 1.f) * C[j][a] * C[KORD - j][b];
      }
      acc += s[j] * T;
    }
    g[m] = acc;
  }
  int any = 0;
  flags[0] = 1;
  for (int m = KORD; m >= 1; --m) {
    if (g[m] != 0.f) any = 1;
    flags[m] = any;
  }
}

// ---------------- gated zero of CSR-build scratch ----------------
__global__ __launch_bounds__(256) void zero_kernel(int* __restrict__ p,
                                                   const int* __restrict__ flags,
                                                   int nwords) {
  if (flags[1] == 0) return;
  for (int i = blockIdx.x * 256 + threadIdx.x; i < nwords; i += gridDim.x * 256)
    p[i] = 0;
}

// ---------------- counts: out-degree at src + in-degree at dst ----------------
__global__ __launch_bounds__(256) void cnt_kernel(const int* __restrict__ src,
                                                  const int* __restrict__ dst,
                                                  int* __restrict__ deg_i,
                                                  int* __restrict__ cnt_dst,
                                                  const int* __restrict__ flags, int E) {
  if (flags[1] == 0) return;
  for (int e = blockIdx.x * 256 + threadIdx.x; e < E; e += gridDim.x * 256) {
    atomicAdd(&deg_i[src[e]], 1);
    atomicAdd(&cnt_dst[dst[e]], 1);
  }
}

__global__ __launch_bounds__(256) void dis_kernel(const int* __restrict__ deg_i,
                                                  float* __restrict__ dis,
                                                  const int* __restrict__ flags, int n) {
  if (flags[1] == 0) return;
  for (int i = blockIdx.x * 256 + threadIdx.x; i < n; i += gridDim.x * 256) {
    int d = deg_i[i];
    dis[i] = d > 0 ? 1.0f / sqrtf((float)d) : 0.f;
  }
}

// ---------------- exclusive prefix sum of cnt_dst -> rowptr[0..n] ----------------
__global__ __launch_bounds__(1024) void scan_kernel(const int* __restrict__ cnt,
                                                    int* __restrict__ rowptr,
                                                    const int* __restrict__ flags) {
  if (flags[1] == 0) return;
  __shared__ int part[1024];
  int t = threadIdx.x;
  const int chunk = (NNODES + 1023) / 1024;
  int lo = t * chunk, hi = lo + chunk;
  if (hi > NNODES) hi = NNODES;
  int s = 0;
  for (int i = lo; i < hi; ++i) s += cnt[i];
  part[t] = s;
  __syncthreads();
  for (int off = 1; off < 1024; off <<= 1) {
    int v = (t >= off) ? part[t - off] : 0;
    __syncthreads();
    part[t] += v;
    __syncthreads();
  }
  int run = (t > 0) ? part[t - 1] : 0;
  for (int i = lo; i < hi; ++i) {
    rowptr[i] = run;
    run += cnt[i];
  }
  if (t == 1023) rowptr[NNODES] = run;
}

// ---------------- CSR fill (dst-major): col[pos] = src ----------------
__global__ __launch_bounds__(256) void fill_kernel(const int* __restrict__ src,
                                                   const int* __restrict__ dst,
                                                   const int* __restrict__ rowptr,
                                                   int* __restrict__ tmpc,
                                                   int* __restrict__ col,
                                                   const int* __restrict__ flags, int E) {
  if (flags[1] == 0) return;
  for (int e = blockIdx.x * 256 + threadIdx.x; e < E; e += gridDim.x * 256) {
    int d = dst[e];
    int pos = rowptr[d] + atomicAdd(&tmpc[d], 1);
    col[pos] = src[e];
  }
}

// ---------------- W1 -> transposed bf16, K padded to 512: w1t[c][k] ----------------
__global__ __launch_bounds__(256) void w1t_kernel(const float* __restrict__ W1,
                                                  __bf16* __restrict__ w1t) {
  int idx = blockIdx.x * 256 + threadIdx.x;
  if (idx >= HIDDIM * KPAD) return;
  int c = idx >> 9, k = idx & (KPAD - 1);
  float v = (k < FIN) ? W1[(size_t)k * HIDDIM + c] : 0.f;
  w1t[(size_t)c * KPAD + k] = (__bf16)v;
}

// ---------------- GEMM1: h = relu(x@W1 + b1)  [diagnostic-split form] ----------------
// ZERO LDS, ZERO barriers, max TLP: 1563 blocks x 4 waves, all co-resident
// (~24 waves/CU, launch_bounds(256,6)). Wave owns 16 rows x 64 cols.
// A: nontemporal float4 pairs from x, depth-4 register ring (R10's schedule).
// B: bf16x8 straight from global w1t (64 KB, L1/L2-hot; values identical to
// the former LDS copy -> bitwise-identical MFMA results).
__global__ __launch_bounds__(256, 6) void gemm1_kernel(
    const float* __restrict__ x, const __bf16* __restrict__ w1t,
    const float* __restrict__ b1, float* __restrict__ h, int n) {
  const int t = threadIdx.x;
  const int w = t >> 6, lane = t & 63;
  const int arow = lane & 15;  // A row in wave tile (= C/D col index)
  const int kq = lane >> 4;    // k quarter within a 32-k chunk
  const int rbase = blockIdx.x * 64 + w * 16;
  int gr = rbase + arow;
  if (gr > NNODES - 1) gr = NNODES - 1;  // clamp; output masked below
  const float* xrow = x + (size_t)gr * FIN + kq * 8;

  f32x4 acc[4] = {};
  f32x4 s0a, s0b, s1a, s1b, s2a, s2b, s3a, s3b;
#define LOADNT(p) __builtin_nontemporal_load((const f32x4*)(p))
#define LOAD_PLAIN(A, B, c_)              \
  A = LOADNT(xrow + (c_) * 32);           \
  B = LOADNT(xrow + (c_) * 32 + 4);
#define LOAD_TAIL(A, B)                   \
  {                                       \
    A = LOADNT(xrow + 480);               \
    B = LOADNT(xrow + 484);               \
    int kb = 480 + kq * 8;                \
    if (kb + 0 >= FIN) A[0] = 0.f;        \
    if (kb + 1 >= FIN) A[1] = 0.f;        \
    if (kb + 2 >= FIN) A[2] = 0.f;        \
    if (kb + 3 >= FIN) A[3] = 0.f;        \
    if (kb + 4 >= FIN) B[0] = 0.f;        \
    if (kb + 5 >= FIN) B[1] = 0.f;        \
    if (kb + 6 >= FIN) B[2] = 0.f;        \
    if (kb + 7 >= FIN) B[3] = 0.f;        \
  }
  LOAD_PLAIN(s0a, s0b, 0)
  LOAD_PLAIN(s1a, s1b, 1)
  LOAD_PLAIN(s2a, s2b, 2)
  LOAD_PLAIN(s3a, s3b, 3)

#define DO_CHUNK(c_, QA, QB)                                                       \
  {                                                                                \
    bf16x8 a;                                                                      \
    a[0] = (__bf16)QA[0]; a[1] = (__bf16)QA[1]; a[2] = (__bf16)QA[2];              \
    a[3] = (__bf16)QA[3]; a[4] = (__bf16)QB[0]; a[5] = (__bf16)QB[1];              \
    a[6] = (__bf16)QB[2]; a[7] = (__bf16)QB[3];                                    \
    _Pragma("unroll") for (int ct = 0; ct < 4; ++ct) {                             \
      int col = ct * 16 + arow;                                                    \
      bf16x8 b =                                                                   \
          *(const bf16x8*)(w1t + (size_t)col * KPAD + (c_) * 32 + kq * 8);         \
      acc[ct] = __builtin_amdgcn_mfma_f32_16x16x32_bf16(a, b, acc[ct], 0, 0, 0);   \
    }                                                                              \
  }

  DO_CHUNK(0, s0a, s0b)  LOAD_PLAIN(s0a, s0b, 4)
  DO_CHUNK(1, s1a, s1b)  LOAD_PLAIN(s1a, s1b, 5)
  DO_CHUNK(2, s2a, s2b)  LOAD_PLAIN(s2a, s2b, 6)
  DO_CHUNK(3, s3a, s3b)  LOAD_PLAIN(s3a, s3b, 7)
  DO_CHUNK(4, s0a, s0b)  LOAD_PLAIN(s0a, s0b, 8)
  DO_CHUNK(5, s1a, s1b)  LOAD_PLAIN(s1a, s1b, 9)
  DO_CHUNK(6, s2a, s2b)  LOAD_PLAIN(s2a, s2b, 10)
  DO_CHUNK(7, s3a, s3b)  LOAD_PLAIN(s3a, s3b, 11)
  DO_CHUNK(8, s0a, s0b)  LOAD_PLAIN(s0a, s0b, 12)
  DO_CHUNK(9, s1a, s1b)  LOAD_PLAIN(s1a, s1b, 13)
  DO_CHUNK(10, s2a, s2b) LOAD_PLAIN(s2a, s2b, 14)
  DO_CHUNK(11, s3a, s3b) LOAD_TAIL(s3a, s3b)
  DO_CHUNK(12, s0a, s0b)
  DO_CHUNK(13, s1a, s1b)
  DO_CHUNK(14, s2a, s2b)
  DO_CHUNK(15, s3a, s3b)
#undef DO_CHUNK
#undef LOAD_PLAIN
#undef LOAD_TAIL
#undef LOADNT

  // epilogue: h[row][col] = relu(acc + b1[col]);  C/D: col=lane&15, row=(lane>>4)*4+reg
#pragma unroll
  for (int ct = 0; ct < 4; ++ct) {
    float bv = b1[ct * 16 + arow];
#pragma unroll
    for (int reg = 0; reg < 4; ++reg) {
      int grow = rbase + kq * 4 + reg;
      if (grow < n) {
        float v = acc[ct][reg] + bv;
        h[(size_t)grow * HIDDIM + ct * 16 + arow] = v > 0.f ? v : 0.f;
      }
    }
  }
}

// ---------------- GEMM2: u = h@W2 + b2 ; out = g0*u ----------------
__global__ __launch_bounds__(256) void gemm2_kernel(
    const float* __restrict__ h, const float* __restrict__ W2,
    const float* __restrict__ b2, const float* __restrict__ g,
    float* __restrict__ u, float* __restrict__ out, int n) {
  __shared__ float w2s[HIDDIM * NCLS];
  int t = threadIdx.x;
  for (int i = t; i < HIDDIM * NCLS; i += 256) w2s[i] = W2[i];
  __syncthreads();
  int idx = blockIdx.x * 256 + t;
  int row = idx >> 2, cg = (idx & 3) * 10;
  if (row >= n) return;
  const float4* hrow = (const float4*)(h + (size_t)row * HIDDIM);
  float o[10] = {};
  for (int k4 = 0; k4 < 16; ++k4) {
    float4 a = hrow[k4];
#pragma unroll
    for (int j = 0; j < 10; ++j) {
      o[j] += a.x * w2s[(k4 * 4 + 0) * 40 + cg + j];
      o[j] += a.y * w2s[(k4 * 4 + 1) * 40 + cg + j];
      o[j] += a.z * w2s[(k4 * 4 + 2) * 40 + cg + j];
      o[j] += a.w * w2s[(k4 * 4 + 3) * 40 + cg + j];
    }
  }
  float g0 = g[0];
  float* urow = u + (size_t)row * NCLS + cg;
  float* orow = out + (size_t)row * NCLS + cg;
#pragma unroll
  for (int j = 0; j < 10; ++j) {
    float val = o[j] + b2[cg + j];
    urow[j] = val;
    orow[j] = g0 * val;
  }
}

// ---------------- SpMV step m: uout = D^-1/2 A D^-1/2 uin ; out += g[m]*uout ----------------
// Wave per node (grid-stride); lanes 0..39 own feature columns. Matches reference
// associativity: sum over edges of (dis[src]*uin[src]), then * dis[dst].
__global__ __launch_bounds__(256) void spmv_kernel(
    const int* __restrict__ col, const int* __restrict__ rowptr,
    const float* __restrict__ dis, const float* __restrict__ uin,
    float* __restrict__ uout, float* __restrict__ out, const float* __restrict__ g,
    const int* __restrict__ flags, int m) {
  if (flags[m] == 0) return;
  int lane = threadIdx.x & 63;
  if (lane >= NCLS) return;
  int stride = gridDim.x * 4;
  for (int wid = blockIdx.x * 4 + (threadIdx.x >> 6); wid < NNODES; wid += stride) {
    int lo = rowptr[wid], hi = rowptr[wid + 1];
    float acc = 0.f;
    for (int e = lo; e < hi; ++e) {
      int s = col[e];
      acc += dis[s] * uin[(size_t)s * NCLS + lane];
    }
    acc *= dis[wid];
    size_t idx = (size_t)wid * NCLS + lane;
    uout[idx] = acc;
    out[idx] += g[m] * acc;
  }
}

// ---------------- log_softmax: one 64-lane wave per row (grid-stride) ----------------
__global__ __launch_bounds__(256) void lsm_kernel(const float* __restrict__ out,
                                                  float* __restrict__ lsm, int n) {
  int lane = threadIdx.x & 63;
  int stride = gridDim.x * 4;
  for (int wid = blockIdx.x * 4 + (threadIdx.x >> 6); wid < n; wid += stride) {
    float xv = (lane < NCLS) ? out[(size_t)wid * NCLS + lane] : -INFINITY;
    float mx = xv;
#pragma unroll
    for (int off = 32; off; off >>= 1) mx = fmaxf(mx, __shfl_xor(mx, off));
    float e = (lane < NCLS) ? expf(xv - mx) : 0.f;
    float sum = e;
#pragma unroll
    for (int off = 32; off; off >>= 1) sum += __shfl_xor(sum, off);
    float lse = logf(sum);
    if (lane < NCLS) lsm[(size_t)wid * NCLS + lane] = xv - mx - lse;
  }
}

extern "C" void kernel_launch(void* const* d_in, const int* in_sizes, int n_in,
                              void* d_out, int out_size, void* d_ws, size_t ws_size,
                              hipStream_t stream) {
  (void)n_in; (void)out_size; (void)ws_size;
  const float* x = (const float*)d_in[0];
  const int* ei = (const int*)d_in[1];
  const float* W1 = (const float*)d_in[2];
  const float* b1 = (const float*)d_in[3];
  const float* W2 = (const float*)d_in[4];
  const float* b2 = (const float*)d_in[5];
  const float* temp = (const float*)d_in[6];
  int E = in_sizes[1] / 2;
  const int* src = ei;
  const int* dst = ei + E;
  int n = NNODES;

  // ws layout in 4-byte words; total ~14.1M words (~56.5 MB)
  float* ws = (float*)d_ws;
  float* ua = ws;                          // 4,000,000 f32
  int* col = (int*)(ws + 4000000);         // 3,200,000 i32
  int* cnt_dst = (int*)(ws + 7200000);     // 100,000 i32 (zero_kernel covers this + next two)
  int* tmpc = (int*)(ws + 7300000);        // 100,000 i32
  int* deg_i = (int*)(ws + 7400000);       // 100,000 i32
  int* rowptr = (int*)(ws + 7500000);      // 100,001 i32
  float* dis = ws + 7600016;               // 100,000 f32
  float* g = ws + 7700016;                 // 16 f32
  int* flags = (int*)(ws + 7700032);       // 16 i32
  __bf16* w1t = (__bf16*)(ws + 7700048);   // 32,768 bf16 = 16,384 words
  float* hbuf = ws + 7716448;              // 6,400,000 f32 (h = relu(x@W1+b1))

  float* lsm = (float*)d_out;            // n*40, also ping-pong scratch during prop
  float* out = (float*)d_out + 4000000;  // n*40 accumulator, final output 1

  coeff_kernel<<<1, 64, 0, stream>>>(temp, g, flags);
  zero_kernel<<<64, 256, 0, stream>>>(cnt_dst, flags, 300000);
  cnt_kernel<<<128, 256, 0, stream>>>(src, dst, deg_i, cnt_dst, flags, E);
  dis_kernel<<<64, 256, 0, stream>>>(deg_i, dis, flags, n);
  scan_kernel<<<1, 1024, 0, stream>>>(cnt_dst, rowptr, flags);
  fill_kernel<<<128, 256, 0, stream>>>(src, dst, rowptr, tmpc, col, flags, E);
  w1t_kernel<<<(HIDDIM * KPAD + 255) / 256, 256, 0, stream>>>(W1, w1t);
  gemm1_kernel<<<(n + 63) / 64, 256, 0, stream>>>(x, w1t, b1, hbuf, n);
  gemm2_kernel<<<(n * 4 + 255) / 256, 256, 0, stream>>>(hbuf, W2, b2, g, ua, out, n);
  for (int m = 1; m <= KORD; ++m) {
    float* uin = (m & 1) ? ua : lsm;
    float* uout = (m & 1) ? lsm : ua;
    spmv_kernel<<<256, 256, 0, stream>>>(col, rowptr, dis, uin, uout, out, g, flags, m);
  }
  lsm_kernel<<<1024, 256, 0, stream>>>(out, lsm, n);
}

// Round 12
// 196.644 us; speedup vs baseline: 1.1846x; 1.1846x over previous
//
#include <hip/hip_runtime.h>
#include <hip/hip_bf16.h>
#include <math.h>

#define NNODES 100000
#define FIN 500
#define KPAD 512
#define HIDDIM 64
#define NCLS 40
#define KORD 10
#define TILES 6250  // NNODES / 16

typedef __bf16 bf16x4 __attribute__((ext_vector_type(4)));
typedef __bf16 bf16x8 __attribute__((ext_vector_type(8)));
typedef float f32x4 __attribute__((ext_vector_type(4)));

// ---------------- polynomial coefficients + need-flags from temp ----------------
// out = sum_j C(K,j)/2^K * relu(temp[j]) * (I-A)^j (I+A)^{K-j} h = sum_m g[m] A^m h
// g[m] = sum_j s_j * T[j][m], T[j][m] = coeff of x^m in (1-x)^j (1+x)^{K-j}.
// All intermediates are integers/1024 with numerators < 2^24, exact in f32.
// flags[m] = 1 iff any g[j] != 0 for j >= m  (SpMV step m still needed).
__global__ void coeff_kernel(const float* __restrict__ temp, float* __restrict__ g,
                             int* __restrict__ flags) {
  if (threadIdx.x != 0 || blockIdx.x != 0) return;
  float C[KORD + 1][KORD + 1];
  for (int n = 0; n <= KORD; ++n)
    for (int k = 0; k <= KORD; ++k) C[n][k] = 0.f;
  for (int n = 0; n <= KORD; ++n) {
    C[n][0] = 1.f;
    for (int k = 1; k <= n; ++k) C[n][k] = C[n - 1][k - 1] + C[n - 1][k];
  }
  float s[KORD + 1];
  for (int j = 0; j <= KORD; ++j) {
    float th = temp[j] > 0.f ? temp[j] : 0.f;
    s[j] = C[KORD][j] * (1.0f / 1024.0f) * th;
  }
  for (int m = 0; m <= KORD; ++m) {
    float acc = 0.f;
    for (int j = 0; j <= KORD; ++j) {
      float T = 0.f;
      for (int a = 0; a <= m; ++a) {
        int b = m - a;
        if (a <= j && b <= KORD - j)
          T += ((a & 1) ? -1.f : 1.f) * C[j][a] * C[KORD - j][b];
      }
      acc += s[j] * T;
    }
    g[m] = acc;
  }
  int any = 0;
  flags[0] = 1;
  for (int m = KORD; m >= 1; --m) {
    if (g[m] != 0.f) any = 1;
    flags[m] = any;
  }
}

// ---------------- gated zero of CSR-build scratch ----------------
__global__ __launch_bounds__(256) void zero_kernel(int* __restrict__ p,
                                                   const int* __restrict__ flags,
                                                   int nwords) {
  if (flags[1] == 0) return;
  for (int i = blockIdx.x * 256 + threadIdx.x; i < nwords; i += gridDim.x * 256)
    p[i] = 0;
}

// ---------------- counts: out-degree at src + in-degree at dst ----------------
__global__ __launch_bounds__(256) void cnt_kernel(const int* __restrict__ src,
                                                  const int* __restrict__ dst,
                                                  int* __restrict__ deg_i,
                                                  int* __restrict__ cnt_dst,
                                                  const int* __restrict__ flags, int E) {
  if (flags[1] == 0) return;
  for (int e = blockIdx.x * 256 + threadIdx.x; e < E; e += gridDim.x * 256) {
    atomicAdd(&deg_i[src[e]], 1);
    atomicAdd(&cnt_dst[dst[e]], 1);
  }
}

__global__ __launch_bounds__(256) void dis_kernel(const int* __restrict__ deg_i,
                                                  float* __restrict__ dis,
                                                  const int* __restrict__ flags, int n) {
  if (flags[1] == 0) return;
  for (int i = blockIdx.x * 256 + threadIdx.x; i < n; i += gridDim.x * 256) {
    int d = deg_i[i];
    dis[i] = d > 0 ? 1.0f / sqrtf((float)d) : 0.f;
  }
}

// ---------------- exclusive prefix sum of cnt_dst -> rowptr[0..n] ----------------
__global__ __launch_bounds__(1024) void scan_kernel(const int* __restrict__ cnt,
                                                    int* __restrict__ rowptr,
                                                    const int* __restrict__ flags) {
  if (flags[1] == 0) return;
  __shared__ int part[1024];
  int t = threadIdx.x;
  const int chunk = (NNODES + 1023) / 1024;
  int lo = t * chunk, hi = lo + chunk;
  if (hi > NNODES) hi = NNODES;
  int s = 0;
  for (int i = lo; i < hi; ++i) s += cnt[i];
  part[t] = s;
  __syncthreads();
  for (int off = 1; off < 1024; off <<= 1) {
    int v = (t >= off) ? part[t - off] : 0;
    __syncthreads();
    part[t] += v;
    __syncthreads();
  }
  int run = (t > 0) ? part[t - 1] : 0;
  for (int i = lo; i < hi; ++i) {
    rowptr[i] = run;
    run += cnt[i];
  }
  if (t == 1023) rowptr[NNODES] = run;
}

// ---------------- CSR fill (dst-major): col[pos] = src ----------------
__global__ __launch_bounds__(256) void fill_kernel(const int* __restrict__ src,
                                                   const int* __restrict__ dst,
                                                   const int* __restrict__ rowptr,
                                                   int* __restrict__ tmpc,
                                                   int* __restrict__ col,
                                                   const int* __restrict__ flags, int E) {
  if (flags[1] == 0) return;
  for (int e = blockIdx.x * 256 + threadIdx.x; e < E; e += gridDim.x * 256) {
    int d = dst[e];
    int pos = rowptr[d] + atomicAdd(&tmpc[d], 1);
    col[pos] = src[e];
  }
}

// ---------------- W1 -> transposed bf16, K padded to 512: w1t[c][k] ----------------
__global__ __launch_bounds__(256) void w1t_kernel(const float* __restrict__ W1,
                                                  __bf16* __restrict__ w1t) {
  int idx = blockIdx.x * 256 + threadIdx.x;
  if (idx >= HIDDIM * KPAD) return;
  int c = idx >> 9, k = idx & (KPAD - 1);
  float v = (k < FIN) ? W1[(size_t)k * HIDDIM + c] : 0.f;
  w1t[(size_t)c * KPAD + k] = (__bf16)v;
}

// ---------------- pack: x (f32 row-major) -> xpk (bf16, MFMA-fragment-major) ----------------
// Tile = 16 rows. For tile T, chunk c (32 k), lane l: xpk[T*8192 + c*512 + l*8 .. +7]
// = bf16(x[T*16 + (l&15)][c*32 + (l>>4)*8 .. +7]), zeros for k >= 500.
// BOTH the x read (linear float4, 1 KB/wave-instr) and the xpk write (lane-contiguous,
// 1 KB/wave-instr) are fully coalesced -- this removes the 16-segment scatter that
// capped every previous variant at ~1.7 TB/s. Transpose happens through LDS.
__global__ __launch_bounds__(256) void pack_kernel(const float* __restrict__ x,
                                                   __bf16* __restrict__ xpk) {
  __shared__ float lds[16][516];  // pitch 516: bank stride 4 -> <=2-way conflicts
  const int tile = blockIdx.x;
  const int t = threadIdx.x;
  const float4* xs = (const float4*)(x + (size_t)tile * 8000);
  for (int j = t; j < 2000; j += 256) {  // 16 rows * 125 float4, coalesced
    float4 q = xs[j];
    int row = j / 125, c4 = j - row * 125;
    *(float4*)&lds[row][c4 * 4] = q;
  }
  // zero k = 500..515 for every row (chunk 15 reads up to col 511)
  lds[t >> 4][500 + (t & 15)] = 0.f;
  __syncthreads();

  const int w = t >> 6, lane = t & 63;
  const int r = lane & 15, kq = lane >> 4;
#pragma unroll
  for (int i = 0; i < 4; ++i) {
    int c = i * 4 + w;
    int cc = c * 32 + kq * 8;
    float4 a0 = *(const float4*)&lds[r][cc];
    float4 a1 = *(const float4*)&lds[r][cc + 4];
    bf16x8 v;
    v[0] = (__bf16)a0.x; v[1] = (__bf16)a0.y; v[2] = (__bf16)a0.z; v[3] = (__bf16)a0.w;
    v[4] = (__bf16)a1.x; v[5] = (__bf16)a1.y; v[6] = (__bf16)a1.z; v[7] = (__bf16)a1.w;
    *(bf16x8*)(xpk + (size_t)tile * 8192 + c * 512 + lane * 8) = v;
  }
}

// ---------------- fused MLP: u = relu(x@W1+b1)@W2+b2 ; out = g0*u ----------------
// 512 threads = 8 waves; wave w owns tile T = blockIdx*8+w (16 rows x 64 cols).
// A: ONE contiguous bf16x8 load per wave-instr from xpk (depth-4 static ring,
// vmcnt tracks only the A ring). B: w1t in LDS (64 KB, XOR-swizzled; lgkmcnt,
// independent of vmcnt). No cvt in the loop (pack did it). Epilogue: barrier,
// arena reused for hs[128][66] + w2s, GEMM2, fused out = g0*u.
__global__ __launch_bounds__(512, 4) void gemm1_kernel(
    const __bf16* __restrict__ xpk, const __bf16* __restrict__ w1t,
    const float* __restrict__ b1, const float* __restrict__ W2,
    const float* __restrict__ b2, const float* __restrict__ g,
    float* __restrict__ u, float* __restrict__ out, int n) {
  __shared__ __align__(16) char arena[65536];
  const int t = threadIdx.x;
  const int w = t >> 6, lane = t & 63;

  // stage w1t (64 cols x 512 k) swizzled: unit uu of col c at slot uu^(c&7)
#pragma unroll
  for (int i = 0; i < 8; ++i) {
    int id = t + 512 * i;  // 16B chunk id, 0..4095
    int c = id >> 6, unit = id & 63;
    bf16x8 v = *(const bf16x8*)(w1t + (size_t)id * 8);
    *(bf16x8*)(arena + c * 1024 + ((unit ^ (c & 7)) << 4)) = v;
  }
  __syncthreads();

  const int arow = lane & 15;  // C/D col index component
  const int kq = lane >> 4;    // k quarter
  const int T = blockIdx.x * 8 + w;
  f32x4 acc[4] = {};

  if (T < TILES) {
    const __bf16* abase = xpk + (size_t)T * 8192 + lane * 8;
    bf16x8 a0 = *(const bf16x8*)(abase);
    bf16x8 a1 = *(const bf16x8*)(abase + 512);
    bf16x8 a2 = *(const bf16x8*)(abase + 1024);
    bf16x8 a3 = *(const bf16x8*)(abase + 1536);

#define DO_CHUNK(c_, R)                                                           \
  {                                                                               \
    int uu = (c_) * 4 + kq;                                                       \
    _Pragma("unroll") for (int ct = 0; ct < 4; ++ct) {                            \
      int col = ct * 16 + arow;                                                   \
      bf16x8 b = *(const bf16x8*)(arena + col * 1024 + ((uu ^ (col & 7)) << 4));  \
      acc[ct] = __builtin_amdgcn_mfma_f32_16x16x32_bf16(R, b, acc[ct], 0, 0, 0);  \
    }                                                                             \
  }
    DO_CHUNK(0, a0)  a0 = *(const bf16x8*)(abase + 4 * 512);
    DO_CHUNK(1, a1)  a1 = *(const bf16x8*)(abase + 5 * 512);
    DO_CHUNK(2, a2)  a2 = *(const bf16x8*)(abase + 6 * 512);
    DO_CHUNK(3, a3)  a3 = *(const bf16x8*)(abase + 7 * 512);
    DO_CHUNK(4, a0)  a0 = *(const bf16x8*)(abase + 8 * 512);
    DO_CHUNK(5, a1)  a1 = *(const bf16x8*)(abase + 9 * 512);
    DO_CHUNK(6, a2)  a2 = *(const bf16x8*)(abase + 10 * 512);
    DO_CHUNK(7, a3)  a3 = *(const bf16x8*)(abase + 11 * 512);
    DO_CHUNK(8, a0)  a0 = *(const bf16x8*)(abase + 12 * 512);
    DO_CHUNK(9, a1)  a1 = *(const bf16x8*)(abase + 13 * 512);
    DO_CHUNK(10, a2) a2 = *(const bf16x8*)(abase + 14 * 512);
    DO_CHUNK(11, a3) a3 = *(const bf16x8*)(abase + 15 * 512);
    DO_CHUNK(12, a0)
    DO_CHUNK(13, a1)
    DO_CHUNK(14, a2)
    DO_CHUNK(15, a3)
#undef DO_CHUNK
  }
  __syncthreads();  // all B reads done; arena reused

  // epilogue: hs = relu(acc + b1) -> LDS [128][66]; w2s copy; GEMM2; out = g0*u
  float* hs = (float*)arena;              // 128*66*4 = 33792 B
  float* w2s = (float*)(arena + 36864);   // 64*40*4 = 10240 B
  for (int i = t; i < HIDDIM * NCLS; i += 512) w2s[i] = W2[i];
  {
#pragma unroll
    for (int ct = 0; ct < 4; ++ct) {
      float bv = b1[ct * 16 + arow];  // C/D col = lane&15
#pragma unroll
      for (int reg = 0; reg < 4; ++reg) {
        int rrow = w * 16 + kq * 4 + reg;  // C/D row = (lane>>4)*4 + reg
        float v = acc[ct][reg] + bv;
        hs[rrow * 66 + ct * 16 + arow] = v > 0.f ? v : 0.f;
      }
    }
  }
  __syncthreads();

  int row = t >> 2, cg = (t & 3) * 10;  // 128 rows x 4 col-groups
  float o[10] = {};
  for (int k = 0; k < HIDDIM; ++k) {
    float a = hs[row * 66 + k];
#pragma unroll
    for (int j = 0; j < 10; ++j) o[j] += a * w2s[k * 40 + cg + j];
  }
  int gr2 = blockIdx.x * 128 + row;
  if (gr2 < n) {
    float g0 = g[0];
    float* urow = u + (size_t)gr2 * NCLS + cg;
    float* orow = out + (size_t)gr2 * NCLS + cg;
#pragma unroll
    for (int j = 0; j < 10; ++j) {
      float val = o[j] + b2[cg + j];
      urow[j] = val;
      orow[j] = g0 * val;
    }
  }
}

// ---------------- SpMV step m: uout = D^-1/2 A D^-1/2 uin ; out += g[m]*uout ----------------
// Wave per node (grid-stride); lanes 0..39 own feature columns. Matches reference
// associativity: sum over edges of (dis[src]*uin[src]), then * dis[dst].
__global__ __launch_bounds__(256) void spmv_kernel(
    const int* __restrict__ col, const int* __restrict__ rowptr,
    const float* __restrict__ dis, const float* __restrict__ uin,
    float* __restrict__ uout, float* __restrict__ out, const float* __restrict__ g,
    const int* __restrict__ flags, int m) {
  if (flags[m] == 0) return;
  int lane = threadIdx.x & 63;
  if (lane >= NCLS) return;
  int stride = gridDim.x * 4;
  for (int wid = blockIdx.x * 4 + (threadIdx.x >> 6); wid < NNODES; wid += stride) {
    int lo = rowptr[wid], hi = rowptr[wid + 1];
    float acc = 0.f;
    for (int e = lo; e < hi; ++e) {
      int s = col[e];
      acc += dis[s] * uin[(size_t)s * NCLS + lane];
    }
    acc *= dis[wid];
    size_t idx = (size_t)wid * NCLS + lane;
    uout[idx] = acc;
    out[idx] += g[m] * acc;
  }
}

// ---------------- log_softmax: one 64-lane wave per row (grid-stride) ----------------
__global__ __launch_bounds__(256) void lsm_kernel(const float* __restrict__ out,
                                                  float* __restrict__ lsm, int n) {
  int lane = threadIdx.x & 63;
  int stride = gridDim.x * 4;
  for (int wid = blockIdx.x * 4 + (threadIdx.x >> 6); wid < n; wid += stride) {
    float xv = (lane < NCLS) ? out[(size_t)wid * NCLS + lane] : -INFINITY;
    float mx = xv;
#pragma unroll
    for (int off = 32; off; off >>= 1) mx = fmaxf(mx, __shfl_xor(mx, off));
    float e = (lane < NCLS) ? expf(xv - mx) : 0.f;
    float sum = e;
#pragma unroll
    for (int off = 32; off; off >>= 1) sum += __shfl_xor(sum, off);
    float lse = logf(sum);
    if (lane < NCLS) lsm[(size_t)wid * NCLS + lane] = xv - mx - lse;
  }
}

extern "C" void kernel_launch(void* const* d_in, const int* in_sizes, int n_in,
                              void* d_out, int out_size, void* d_ws, size_t ws_size,
                              hipStream_t stream) {
  (void)n_in; (void)out_size; (void)ws_size;
  const float* x = (const float*)d_in[0];
  const int* ei = (const int*)d_in[1];
  const float* W1 = (const float*)d_in[2];
  const float* b1 = (const float*)d_in[3];
  const float* W2 = (const float*)d_in[4];
  const float* b2 = (const float*)d_in[5];
  const float* temp = (const float*)d_in[6];
  int E = in_sizes[1] / 2;
  const int* src = ei;
  const int* dst = ei + E;
  int n = NNODES;

  // ws layout in 4-byte words; total ~33.4M words (~134 MB)
  float* ws = (float*)d_ws;
  float* ua = ws;                          // 4,000,000 f32
  int* col = (int*)(ws + 4000000);         // 3,200,000 i32
  int* cnt_dst = (int*)(ws + 7200000);     // 100,000 i32 (zero_kernel covers this + next two)
  int* tmpc = (int*)(ws + 7300000);        // 100,000 i32
  int* deg_i = (int*)(ws + 7400000);       // 100,000 i32
  int* rowptr = (int*)(ws + 7500000);      // 100,001 i32
  float* dis = ws + 7600016;               // 100,000 f32
  float* g = ws + 7700016;                 // 16 f32
  int* flags = (int*)(ws + 7700032);       // 16 i32
  __bf16* w1t = (__bf16*)(ws + 7700048);   // 32,768 bf16 = 16,384 words
  __bf16* xpk = (__bf16*)(ws + 7716448);   // 51,200,000 bf16 = 25,600,000 words

  float* lsm = (float*)d_out;            // n*40, also ping-pong scratch during prop
  float* out = (float*)d_out + 4000000;  // n*40 accumulator, final output 1

  coeff_kernel<<<1, 64, 0, stream>>>(temp, g, flags);
  zero_kernel<<<64, 256, 0, stream>>>(cnt_dst, flags, 300000);
  cnt_kernel<<<128, 256, 0, stream>>>(src, dst, deg_i, cnt_dst, flags, E);
  dis_kernel<<<64, 256, 0, stream>>>(deg_i, dis, flags, n);
  scan_kernel<<<1, 1024, 0, stream>>>(cnt_dst, rowptr, flags);
  fill_kernel<<<128, 256, 0, stream>>>(src, dst, rowptr, tmpc, col, flags, E);
  w1t_kernel<<<(HIDDIM * KPAD + 255) / 256, 256, 0, stream>>>(W1, w1t);
  pack_kernel<<<TILES, 256, 0, stream>>>(x, xpk);
  gemm1_kernel<<<(TILES + 7) / 8, 512, 0, stream>>>(xpk, w1t, b1, W2, b2, g, ua, out, n);
  for (int m = 1; m <= KORD; ++m) {
    float* uin = (m & 1) ? ua : lsm;
    float* uout = (m & 1) ? lsm : ua;
    spmv_kernel<<<256, 256, 0, stream>>>(col, rowptr, dis, uin, uout, out, g, flags, m);
  }
  lsm_kernel<<<1024, 256, 0, stream>>>(out, lsm, n);
}